// Round 7
// baseline (181.646 us; speedup 1.0000x reference)
//
#include <hip/hip_runtime.h>
#include <stdint.h>

#define NQ   8192
#define NB   2
#define KNN  10
#define K1   11                 // top-11 incl. self (d=0); self dropped in loss
#define NTOT (NB * NQ)
#define NGR  (NTOT / 64)        // 256 query groups of 64 sorted queries
#define IDXMASK 0x1FFFu

// x-bucketing
#define NBUK  2048
#define XMIN  (-6.0f)
#define BSCALE ((float)NBUK / 12.0f)

// scan2: 512 blocks = (group, parity); 8 waves (512 threads) each
#define SW    8
#define SGRID (NGR * 2)
#define CHK   1024              // parity-candidates per LDS chunk (covers 2048 positions)
#define CAP   16                // self-draining private list per (wave,lane)
#define LSTR  17                // odd stride -> conflict-free
#define SENT  5e18f
#define CKI(s, c, lane) ((((s) * SW) + (c)) * 64 + (lane))

static __device__ __forceinline__ uint32_t umin32(uint32_t a, uint32_t b) { return a < b ? a : b; }
static __device__ __forceinline__ uint32_t umax32(uint32_t a, uint32_t b) { return a > b ? a : b; }

static __device__ __forceinline__ void insert11(uint32_t (&l)[K1], uint32_t key) {
#pragma unroll
    for (int s = 0; s < K1; ++s) {
        const uint32_t m = l[s];
        l[s] = umin32(key, m);
        key  = umax32(key, m);
    }
}

static __device__ __forceinline__ int bucket_of(float x) {
    int bb = (int)floorf((x - XMIN) * BSCALE);
    return bb < 0 ? 0 : (bb > NBUK - 1 ? NBUK - 1 : bb);
}

// ---------------- k_prep: per-batch hist -> prefix -> scatter, all in one block ----------------
__global__ __launch_bounds__(1024) void k_prep(
    const float* __restrict__ p1, float4* __restrict__ srt,
    uint32_t* __restrict__ boff, uint32_t* __restrict__ flags, float* __restrict__ out)
{
    __shared__ uint32_t h0[NBUK], h1[NBUK];            // 16 KB
    const int tid = threadIdx.x;
    const int b   = blockIdx.x;
    const float* __restrict__ P = p1 + (size_t)b * NQ * 3;

    if (b == 0) {                                      // zero pair-flags and the output
        if (tid < NGR) flags[tid] = 0u;
        if (tid == 0)  out[0] = 0.0f;
    }
    h0[tid] = 0u; h0[tid + 1024] = 0u;
    __syncthreads();

    float px[8], py[8], pz[8]; int bk[8];
#pragma unroll
    for (int r = 0; r < 8; ++r) {
        const int i = tid + r * 1024;
        px[r] = P[i * 3 + 0]; py[r] = P[i * 3 + 1]; pz[r] = P[i * 3 + 2];
        bk[r] = bucket_of(px[r]);
        atomicAdd(&h0[bk[r]], 1u);
    }
    __syncthreads();

    uint32_t* s0 = h0; uint32_t* s1 = h1;              // Hillis-Steele inclusive scan
    for (int s = 1; s < NBUK; s <<= 1) {
        for (int i = tid; i < NBUK; i += 1024)
            s1[i] = s0[i] + (i >= s ? s0[i - s] : 0u);
        __syncthreads();
        uint32_t* t = s0; s0 = s1; s1 = t;
    }
    uint32_t* BO = boff + (size_t)b * (NBUK + 1);
    for (int i = tid; i < NBUK; i += 1024) {
        BO[i + 1] = s0[i];
        s1[i]     = (i == 0) ? 0u : s0[i - 1];         // exclusive cursors in LDS
    }
    if (tid == 0) BO[0] = 0u;
    __syncthreads();

    float4* __restrict__ S = srt + (size_t)b * NQ;
#pragma unroll
    for (int r = 0; r < 8; ++r) {
        const uint32_t pos = atomicAdd(&s1[bk[r]], 1u);
        S[pos] = make_float4(px[r], py[r], pz[r], __uint_as_float((uint32_t)(tid + r * 1024)));
    }
}

// ---------------- k_scan2: tau -> parity window scan -> partial top-11; last finisher merges + loss ----------------
__global__ __launch_bounds__(512, 4) void k_scan2(
    const float4* __restrict__ srt, const uint32_t* __restrict__ boff,
    const float* __restrict__ p1, const float* __restrict__ p2,
    uint32_t* __restrict__ keysG, uint32_t* __restrict__ flags,
    float* __restrict__ out)
{
    __shared__ __align__(16) float4 win[CHK];          // 16 KB: samples / candidate chunks
    __shared__ uint32_t scratch[SW * 64 * LSTR];       // 34.8 KB: lists + tree scratch (aliased)
    __shared__ float    tauF[64];
    __shared__ uint32_t sflag[1];                      // total ~51.3 KB -> 2+ blocks/CU

    const int tid  = threadIdx.x;
    const int lane = tid & 63;
    const int w    = tid >> 6;
    const int wq   = __builtin_amdgcn_readfirstlane(w);
    const int g    = blockIdx.x >> 1;                  // group 0..255
    const int h    = blockIdx.x & 1;                   // parity of sorted positions to scan
    const int b    = g >> 7;
    const int q0   = (g & 127) << 6;
    const float4*   __restrict__ S  = srt  + (size_t)b * NQ;
    const uint32_t* __restrict__ BO = boff + (size_t)b * (NBUK + 1);

    const float4 Q = S[q0 + lane];                     // my query (.w = original idx)
    const float qx = Q.x, qy = Q.y, qz = Q.z;
    const uint32_t qidO = __float_as_uint(Q.w);

    // ---- stage 512 samples: 32 runs of 16 consecutive, run stride 256, parity offset ----
    win[tid] = S[((tid >> 4) << 8) + (h << 7) + (tid & 15)];
    __syncthreads();

    uint32_t F[K1];
    // ---- tau: per-wave top-11 of 64 samples (valid upper bound on d11), tree 8->1 ----
    {
        uint32_t l[K1];
#pragma unroll
        for (int s = 0; s < K1; ++s) l[s] = 0xFFFFFFFFu;
#pragma unroll 4
        for (int i = 0; i < 64; ++i) {
            const float4 C = win[(wq << 6) | i];       // broadcast ds_read_b128, imm offsets
            const float dx = qx - C.x, dy = qy - C.y, dz = qz - C.z;
            const float d  = fmaf(dx, dx, fmaf(dy, dy, dz * dz));
            insert11(l, __float_as_uint(d));
        }
#pragma unroll
        for (int s = 0; s < K1; ++s) scratch[CKI(s, wq, lane)] = l[s];
        for (int st = 1; st < SW; st <<= 1) {
            __syncthreads();
            if ((wq & (2 * st - 1)) == 0) {
#pragma unroll
                for (int e = 0; e < K1; ++e) insert11(l, scratch[CKI(e, wq + st, lane)]);
                if (2 * st < SW) {
#pragma unroll
                    for (int s = 0; s < K1; ++s) scratch[CKI(s, wq, lane)] = l[s];
                } else {
                    tauF[lane] = __uint_as_float(l[K1 - 1] | IDXMASK);
                }
            }
        }
        __syncthreads();
    }

    const float tauUpF = tauF[lane];                   // trunc-space superset bound
    // ---- block union window in x (identical across waves; +ulp guard on sqrt) ----
    const float sL = sqrtf(tauUpF) * 1.0001f;
    float smax = sL, xmn = qx, xmx = qx;
#pragma unroll
    for (int off = 32; off > 0; off >>= 1) {
        smax = fmaxf(smax, __shfl_xor(smax, off, 64));
        xmn  = fminf(xmn,  __shfl_xor(xmn,  off, 64));
        xmx  = fmaxf(xmx,  __shfl_xor(xmx,  off, 64));
    }
    const int blo = bucket_of(xmn - smax);
    const int bhi = bucket_of(xmx + smax);
    const uint32_t wlo = BO[blo];
    const uint32_t whi = BO[bhi + 1];
    const uint32_t p0     = wlo + ((wlo ^ (uint32_t)h) & 1u);   // first pos >= wlo with parity h
    const uint32_t kcount = (whi > p0) ? ((whi - p0 + 1u) >> 1) : 0u;

    // ---- chunked parity scan: unconditional append, branch-free count ----
#pragma unroll
    for (int s = 0; s < K1; ++s) F[s] = 0xFFFFFFFFu;
    const uint32_t lbase = (uint32_t)(wq * 64 + lane) * LSTR;
    uint32_t cnt = 0;

    for (uint32_t k0 = 0; k0 < kcount; k0 += CHK) {
        __syncthreads();                               // prev chunk / samples consumed
        for (int i = tid; i < CHK; i += 512) {
            const uint32_t k = k0 + (uint32_t)i;
            win[i] = (k < kcount) ? S[p0 + 2u * k] : make_float4(SENT, SENT, SENT, 0.f);
        }
        __syncthreads();

#pragma unroll 4
        for (int t = 0; t < CHK / SW; ++t) {           // 128 static iters
            const float4 C = win[(t << 3) | wq];       // broadcast ds_read_b128, imm offsets
            const float dx = qx - C.x, dy = qy - C.y, dz = qz - C.z;
            const float d  = fmaf(dx, dx, fmaf(dy, dy, dz * dz));
            scratch[lbase + cnt] = (__float_as_uint(d) & ~IDXMASK)
                                 | (__float_as_uint(C.w) & IDXMASK);
            cnt += (d <= tauUpF) ? 1u : 0u;            // slot claimed only on pass
            if (cnt == CAP) {                          // rare: drain to registers
#pragma unroll 1
                for (int s2 = 0; s2 < CAP; ++s2) insert11(F, scratch[lbase + s2]);
                cnt = 0;
            }
        }
    }
#pragma unroll 1
    for (uint32_t s = 0; s < cnt; ++s) insert11(F, scratch[lbase + s]);
    __syncthreads();                                   // all list reads done before tree reuse

    // ---- tree merge 8 -> 1 (wave 0 ends holding the block-partial top-11) ----
#pragma unroll
    for (int s = 0; s < K1; ++s) scratch[CKI(s, wq, lane)] = F[s];
    for (int st = 1; st < SW; st <<= 1) {
        __syncthreads();
        if ((wq & (2 * st - 1)) == 0) {
#pragma unroll
            for (int e = 0; e < K1; ++e) insert11(F, scratch[CKI(e, wq + st, lane)]);
            if (2 * st < SW) {
#pragma unroll
                for (int s = 0; s < K1; ++s) scratch[CKI(s, wq, lane)] = F[s];
            }
        }
    }

    // ---- publish partials; last finisher of the pair merges + computes loss ----
    // Release/acquire via agent-scope atomics (well-defined across non-coherent XCD L2s).
    if (wq == 0) {
        uint32_t* dst = keysG + ((size_t)(g * 2 + h) * 64 + lane) * K1;
#pragma unroll
        for (int s = 0; s < K1; ++s)
            __hip_atomic_store(&dst[s], F[s], __ATOMIC_RELAXED, __HIP_MEMORY_SCOPE_AGENT);
    }
    __syncthreads();                                   // all wave-0 stores issued
    if (tid == 0)
        sflag[0] = __hip_atomic_fetch_add(&flags[g], 1u, __ATOMIC_ACQ_REL,
                                          __HIP_MEMORY_SCOPE_AGENT);
    __syncthreads();
    if (sflag[0] == 0) return;                         // first finisher: done (block-uniform)

    if (wq == 0) {
        const uint32_t* src = keysG + ((size_t)(g * 2 + (1 - h)) * 64 + lane) * K1;
#pragma unroll
        for (int s = 0; s < K1; ++s)
            insert11(F, __hip_atomic_load(&src[s], __ATOMIC_RELAXED,
                                          __HIP_MEMORY_SCOPE_AGENT));

        const float* __restrict__ P1 = p1 + (size_t)b * NQ * 3;
        const float* __restrict__ P2 = p2 + (size_t)b * NQ * 3;
        float s1x = 0.f, s1y = 0.f, s1z = 0.f, s2x = 0.f, s2y = 0.f, s2z = 0.f;
#pragma unroll
        for (int s = 1; s < K1; ++s) {                 // F[0] = self (trunc d = 0)
            const int n = (int)(F[s] & IDXMASK);
            s1x += P1[n * 3 + 0]; s1y += P1[n * 3 + 1]; s1z += P1[n * 3 + 2];
            s2x += P2[n * 3 + 0]; s2y += P2[n * 3 + 1]; s2z += P2[n * 3 + 2];
        }
        const float invk = 1.0f / (float)KNN;
        const float lx = (s1x * invk - qx) - (s2x * invk - P2[qidO * 3 + 0]);
        const float ly = (s1y * invk - qy) - (s2y * invk - P2[qidO * 3 + 1]);
        const float lz = (s1z * invk - qz) - (s2z * invk - P2[qidO * 3 + 2]);
        float acc = fabsf(lx) + fabsf(ly) + fabsf(lz);
#pragma unroll
        for (int off = 32; off > 0; off >>= 1)
            acc += __shfl_down(acc, off, 64);
        if (lane == 0) atomicAdd(out, acc * (1.0f / (float)(NTOT * 3)));
    }
}

extern "C" void kernel_launch(void* const* d_in, const int* in_sizes, int n_in,
                              void* d_out, int out_size, void* d_ws, size_t ws_size,
                              hipStream_t stream) {
    const float* p1 = (const float*)d_in[0];
    const float* p2 = (const float*)d_in[1];
    float* out      = (float*)d_out;

    // ws: srt (256 KB) | boff (16.4 KB) | flags (1 KB) | keysG (1.44 MB)
    float4*   srt   = (float4*)d_ws;
    uint32_t* boff  = (uint32_t*)(srt + (size_t)NB * NQ);
    uint32_t* flags = boff + (size_t)NB * (NBUK + 1);
    uint32_t* keysG = flags + NGR;

    k_prep <<<dim3(NB),    dim3(1024), 0, stream>>>(p1, srt, boff, flags, out);
    k_scan2<<<dim3(SGRID), dim3(512),  0, stream>>>(srt, boff, p1, p2, keysG, flags, out);
}

// Round 8
// 150.065 us; speedup vs baseline: 1.2104x; 1.2104x over previous
//
#include <hip/hip_runtime.h>
#include <stdint.h>

#define NQ   8192
#define NB   2
#define KNN  10
#define K1   11                 // top-11 incl. self (d=0); self dropped in loss
#define NTOT (NB * NQ)
#define IDXMASK 0x1FFFu

// x-bucketing
#define NBUK  2048
#define XMIN  (-6.0f)
#define BSCALE ((float)NBUK / 12.0f)

// k_knn: 1024 blocks x 256 threads; 16 queries/block, 16 subs/query
#define QPB   16
#define NBLK  (NTOT / QPB)      // 1024
#define CSL   512               // central slab for tau (coalesced, local)
#define WCHK  1024              // candidate chunk (16 KB float4)
#define CAP   8                 // private self-draining list per thread
#define LSTR  9                 // odd stride -> conflict-free
#define SENT  5e18f

static __device__ __forceinline__ uint32_t umin32(uint32_t a, uint32_t b) { return a < b ? a : b; }
static __device__ __forceinline__ uint32_t umax32(uint32_t a, uint32_t b) { return a > b ? a : b; }

static __device__ __forceinline__ void insert11(uint32_t (&l)[K1], uint32_t key) {
#pragma unroll
    for (int s = 0; s < K1; ++s) {
        const uint32_t m = l[s];
        l[s] = umin32(key, m);
        key  = umax32(key, m);
    }
}

static __device__ __forceinline__ int bucket_of(float x) {
    int bb = (int)floorf((x - XMIN) * BSCALE);
    return bb < 0 ? 0 : (bb > NBUK - 1 ? NBUK - 1 : bb);
}

// ---------------- k_prep: per-batch hist -> prefix -> scatter (proven r5/r7); zeroes out ----------------
__global__ __launch_bounds__(1024) void k_prep(
    const float* __restrict__ p1, float4* __restrict__ srt,
    uint32_t* __restrict__ boff, float* __restrict__ out)
{
    __shared__ uint32_t h0[NBUK], h1[NBUK];            // 16 KB
    const int tid = threadIdx.x;
    const int b   = blockIdx.x;
    const float* __restrict__ P = p1 + (size_t)b * NQ * 3;

    if (b == 0 && tid == 0) out[0] = 0.0f;
    h0[tid] = 0u; h0[tid + 1024] = 0u;
    __syncthreads();

    float px[8], py[8], pz[8]; int bk[8];
#pragma unroll
    for (int r = 0; r < 8; ++r) {
        const int i = tid + r * 1024;
        px[r] = P[i * 3 + 0]; py[r] = P[i * 3 + 1]; pz[r] = P[i * 3 + 2];
        bk[r] = bucket_of(px[r]);
        atomicAdd(&h0[bk[r]], 1u);
    }
    __syncthreads();

    uint32_t* s0 = h0; uint32_t* s1 = h1;              // Hillis-Steele inclusive scan
    for (int s = 1; s < NBUK; s <<= 1) {
        for (int i = tid; i < NBUK; i += 1024)
            s1[i] = s0[i] + (i >= s ? s0[i - s] : 0u);
        __syncthreads();
        uint32_t* t = s0; s0 = s1; s1 = t;
    }
    uint32_t* BO = boff + (size_t)b * (NBUK + 1);
    for (int i = tid; i < NBUK; i += 1024) {
        BO[i + 1] = s0[i];
        s1[i]     = (i == 0) ? 0u : s0[i - 1];         // exclusive cursors in LDS
    }
    if (tid == 0) BO[0] = 0u;
    __syncthreads();

    float4* __restrict__ S = srt + (size_t)b * NQ;
#pragma unroll
    for (int r = 0; r < 8; ++r) {
        const uint32_t pos = atomicAdd(&s1[bk[r]], 1u);
        S[pos] = make_float4(px[r], py[r], pz[r], __uint_as_float((uint32_t)(tid + r * 1024)));
    }
}

// ---------------- k_knn: 16 queries/block; slab tau -> window scan -> tree merge -> loss ----------------
__global__ __launch_bounds__(256, 4) void k_knn(
    const float4* __restrict__ srt, const uint32_t* __restrict__ boff,
    const float* __restrict__ p1, const float* __restrict__ p2,
    float* __restrict__ out)
{
    __shared__ __align__(16) float4 win[WCHK];         // 16 KB: slab / chunks / tree scratch (aliased)
    __shared__ uint32_t lists[256 * LSTR];             // 9 KB: private survivor lists
    __shared__ uint32_t mins[256];                     // share-minima; later neighbor indices
    __shared__ float    sums[6 * QPB];                 // loss accumulators [comp][q]

    const int tid = threadIdx.x;
    const int q   = tid & 15;                          // query within tile
    const int sub = tid >> 4;                          // 16 subs per query
    const int gq  = blockIdx.x;                        // tile id
    const int b   = gq >> 9;                           // 512 tiles per batch
    const int q0  = (gq & 511) << 4;                   // sorted base position of tile
    const float4*   __restrict__ S  = srt  + (size_t)b * NQ;
    const uint32_t* __restrict__ BO = boff + (size_t)b * (NBUK + 1);
    const float*    __restrict__ P1 = p1 + (size_t)b * NQ * 3;
    const float*    __restrict__ P2 = p2 + (size_t)b * NQ * 3;

    const float4 Q = S[q0 + q];                        // my query (.w = original idx)
    const float qx = Q.x, qy = Q.y, qz = Q.z;

    // ---- stage 512-point central slab (coalesced) ----
    int lo = q0 - 248;
    lo = lo < 0 ? 0 : (lo > NQ - CSL ? NQ - CSL : lo);
    win[tid]       = S[lo + tid];
    win[tid + 256] = S[lo + tid + 256];
    __syncthreads();

    // ---- tau: min over my disjoint 32-point share; 11th of the 16 share-minima ----
    float mn = 1e30f;
#pragma unroll 4
    for (int i = 0; i < 32; ++i) {
        const float4 C = win[(sub << 5) | i];          // 4 addrs/wave, 16-lane broadcast
        const float dx = qx - C.x, dy = qy - C.y, dz = qz - C.z;
        mn = fminf(mn, fmaf(dx, dx, fmaf(dy, dy, dz * dz)));
    }
    mins[tid] = __float_as_uint(mn);                   // mins[sub*16+q] (linear)
    __syncthreads();

    uint32_t F[K1];
#pragma unroll
    for (int s = 0; s < K1; ++s) F[s] = 0xFFFFFFFFu;
#pragma unroll
    for (int s = 0; s < 16; ++s) insert11(F, mins[(s << 4) | q]);   // broadcast reads
    const float tauUp = __uint_as_float(F[K1 - 1] | IDXMASK);       // trunc-space superset bound

    // ---- union window in x over the 16 queries (all present in every wave) ----
    const float sL = sqrtf(tauUp) * 1.0001f;
    float xmn = qx - sL, xmx = qx + sL;
#pragma unroll
    for (int off = 32; off > 0; off >>= 1) {
        xmn = fminf(xmn, __shfl_xor(xmn, off, 64));
        xmx = fmaxf(xmx, __shfl_xor(xmx, off, 64));
    }
    const uint32_t wlo = BO[bucket_of(xmn)];
    const uint32_t whi = BO[bucket_of(xmx) + 1];

    // ---- chunked window scan: conditional append to private list, self-drain (exact) ----
#pragma unroll
    for (int s = 0; s < K1; ++s) F[s] = 0xFFFFFFFFu;
    const uint32_t lbase = (uint32_t)tid * LSTR;
    uint32_t cnt = 0;

    for (uint32_t base = wlo; base < whi; base += WCHK) {
        const int n    = (int)umin32(whi - base, WCHK);
        const int npad = (n + 15) & ~15;
        __syncthreads();                               // prev chunk / slab consumed
        for (int i = tid; i < npad; i += 256)
            win[i] = (i < n) ? S[base + i] : make_float4(SENT, SENT, SENT, 0.f);
        __syncthreads();

        const int iters = npad >> 4;
        for (int t = 0; t < iters; ++t) {
            const float4 C = win[(t << 4) | sub];      // 4 addrs/wave, 16-lane broadcast
            const float dx = qx - C.x, dy = qy - C.y, dz = qz - C.z;
            const float d  = fmaf(dx, dx, fmaf(dy, dy, dz * dz));
            if (d <= tauUp) {                          // ~1.3 hits/thread total
                lists[lbase + cnt] = (__float_as_uint(d) & ~IDXMASK)
                                   | (__float_as_uint(C.w) & IDXMASK);
                if (++cnt == CAP) {                    // rare: drain to registers (exactness)
#pragma unroll
                    for (int s2 = 0; s2 < CAP; ++s2) insert11(F, lists[lbase + s2]);
                    cnt = 0;
                }
            }
        }
    }
    for (uint32_t s = 0; s < cnt; ++s) insert11(F, lists[lbase + s]);
    __syncthreads();                                   // all chunk reads done; win reusable

    // ---- tree merge 16 subs -> 1 per query (scratch aliased into win) ----
    uint32_t* tscr = (uint32_t*)win;                   // 256*11*4 = 11264 B <= 16384 B
#pragma unroll
    for (int s = 0; s < K1; ++s) tscr[((s << 4) | sub) * 16 + q] = F[s];
    for (int st = 1; st < 16; st <<= 1) {
        __syncthreads();
        if ((sub & (2 * st - 1)) == 0) {
#pragma unroll
            for (int e = 0; e < K1; ++e) insert11(F, tscr[((e << 4) | (sub + st)) * 16 + q]);
            if (2 * st < 16) {
#pragma unroll
                for (int s = 0; s < K1; ++s) tscr[((s << 4) | sub) * 16 + q] = F[s];
            }
        }
    }
    __syncthreads();                                   // tree reads done; mins reusable

    // ---- loss: publish neighbor indices, 160-thread parallel gather, finalize ----
    if (sub == 0) {                                    // threads 0..15 hold final top-11
#pragma unroll
        for (int s = 1; s < K1; ++s)                   // F[0] = self (trunc d = 0)
            mins[(s - 1) * 16 + q] = F[s] & IDXMASK;
    }
    if (tid < 96) sums[tid] = 0.0f;
    __syncthreads();
    if (tid < 160) {                                   // qq = tid&15, neighbor j = tid>>4
        const int n = (int)mins[tid];
        const int qq = tid & 15;
        atomicAdd(&sums[0 * 16 + qq], P1[n * 3 + 0]);
        atomicAdd(&sums[1 * 16 + qq], P1[n * 3 + 1]);
        atomicAdd(&sums[2 * 16 + qq], P1[n * 3 + 2]);
        atomicAdd(&sums[3 * 16 + qq], P2[n * 3 + 0]);
        atomicAdd(&sums[4 * 16 + qq], P2[n * 3 + 1]);
        atomicAdd(&sums[5 * 16 + qq], P2[n * 3 + 2]);
    }
    __syncthreads();
    if (sub == 0) {
        const uint32_t qidO = __float_as_uint(Q.w);
        const float invk = 1.0f / (float)KNN;
        const float lx = (sums[0 * 16 + q] * invk - qx) - (sums[3 * 16 + q] * invk - P2[qidO * 3 + 0]);
        const float ly = (sums[1 * 16 + q] * invk - qy) - (sums[4 * 16 + q] * invk - P2[qidO * 3 + 1]);
        const float lz = (sums[2 * 16 + q] * invk - qz) - (sums[5 * 16 + q] * invk - P2[qidO * 3 + 2]);
        float acc = fabsf(lx) + fabsf(ly) + fabsf(lz);
#pragma unroll
        for (int off = 8; off > 0; off >>= 1)          // reduce lanes 0..15 (wave 0)
            acc += __shfl_down(acc, off, 16);
        if (tid == 0) atomicAdd(out, acc * (1.0f / (float)(NTOT * 3)));
    }
}

extern "C" void kernel_launch(void* const* d_in, const int* in_sizes, int n_in,
                              void* d_out, int out_size, void* d_ws, size_t ws_size,
                              hipStream_t stream) {
    const float* p1 = (const float*)d_in[0];
    const float* p2 = (const float*)d_in[1];
    float* out      = (float*)d_out;

    // ws: srt (256 KB) | boff (16.4 KB)
    float4*   srt  = (float4*)d_ws;
    uint32_t* boff = (uint32_t*)(srt + (size_t)NB * NQ);

    k_prep<<<dim3(NB),   dim3(1024), 0, stream>>>(p1, srt, boff, out);
    k_knn <<<dim3(NBLK), dim3(256),  0, stream>>>(srt, boff, p1, p2, out);
}